// Round 10
// baseline (313.172 us; speedup 1.0000x reference)
//
#include <hip/hip_runtime.h>
#include <stdint.h>

#define N_NODES 100000
#define N_EDGES 3200000
#define CH 128
#define NBUK 391          // 256-node buckets
#define CAP 8704          // bucket capacity (mean 8184, +5.7 sigma) -- dataset-fixed, verified rounds 0-9
#define SPLITB 391        // split blocks, 8192 edges each
#define EPB 8192          // edges per split block
#define ROWS_A 50048      // gemm rows done in K2a

typedef __bf16 bf16x8 __attribute__((ext_vector_type(8)));
typedef float  floatx4 __attribute__((ext_vector_type(4)));

__device__ __forceinline__ unsigned short f2bf_bits(float f) {
    unsigned u = __float_as_uint(f);
    u += 0x7FFFu + ((u >> 16) & 1u);
    return (unsigned short)(u >> 16);
}

// monotone encoding: unsigned order == float order
__device__ __forceinline__ unsigned short enc16(unsigned short b) {
    return b ^ ((b & 0x8000u) ? 0xFFFFu : 0x8000u);
}

__device__ __forceinline__ unsigned pkminu(unsigned a, unsigned b) {
    unsigned d;
    asm("v_pk_min_u16 %0, %1, %2" : "=v"(d) : "v"(a), "v"(b));
    return d;
}

// decode both halves back to bf16 bits
__device__ __forceinline__ unsigned dec2(unsigned k) {
    unsigned lo = k & 0xFFFFu;
    unsigned hi = k >> 16;
    lo ^= (lo & 0x8000u) ? 0x8000u : 0xFFFFu;
    hi ^= (hi & 0x8000u) ? 0x8000u : 0xFFFFu;
    return lo | (hi << 16);
}

__device__ __forceinline__ bf16x8 pack8(floatx4 f0, floatx4 f1) {
    bf16x8 r;
    r[0] = (__bf16)f0[0]; r[1] = (__bf16)f0[1]; r[2] = (__bf16)f0[2]; r[3] = (__bf16)f0[3];
    r[4] = (__bf16)f1[0]; r[5] = (__bf16)f1[1]; r[6] = (__bf16)f1[2]; r[7] = (__bf16)f1[3];
    return r;
}

// shared gemm tile body: yt rows [row0, row0+16) = enc(bf16(x @ W_theta^T))
// R10: W_theta consumed as FLOAT, converted in-register (same RNE as the old
// pre-pass) -- k_setup kernel + wb buffer eliminated.
__device__ __forceinline__ void gemm_tile(int row0, int lane, const float* __restrict__ x,
                                          const float* __restrict__ Wt,
                                          unsigned short* __restrict__ yt) {
    int m = lane & 15, quad = lane >> 4;
    bf16x8 a[4];
    const floatx4* xp = (const floatx4*)(x + (size_t)(row0 + m) * CH + quad * 8);
#pragma unroll
    for (int ks = 0; ks < 4; ks++) a[ks] = pack8(xp[ks * 8], xp[ks * 8 + 1]);

    for (int nt = 0; nt < 8; nt++) {
        const floatx4* wp = (const floatx4*)(Wt + (size_t)(nt * 16 + m) * CH + quad * 8);
        floatx4 acc = {0.f, 0.f, 0.f, 0.f};
#pragma unroll
        for (int ks = 0; ks < 4; ks++)
            acc = __builtin_amdgcn_mfma_f32_16x16x32_bf16(
                a[ks], pack8(wp[ks * 8], wp[ks * 8 + 1]), acc, 0, 0, 0);
#pragma unroll
        for (int r = 0; r < 4; r++) {
            int orow = row0 + quad * 4 + r;
            yt[(size_t)orow * CH + nt * 16 + m] = enc16(f2bf_bits(acc[r]));
        }
    }
}

// ---------------- K2a: LDS-staged multi-split (391 x 8192) || gemm [0, ROWS_A) ----
// R8-proven. cursor starts at 0 (memset); base = b*CAP + reserved offset.
// pair = (row&255)<<17 | col  (col < 2^17).
__global__ void k_split_gemmyA(const int* __restrict__ row, const int* __restrict__ col,
                               int* __restrict__ cursor, unsigned* __restrict__ pairs,
                               const float* __restrict__ x,
                               const float* __restrict__ Wt,
                               unsigned short* __restrict__ yt) {
    __shared__ unsigned lpair[EPB];      // 32 KB staged pairs, bucket-sorted
    __shared__ int h[NBUK];
    __shared__ int hb[NBUK];
    __shared__ int lbase[NBUK];
    __shared__ int cur[NBUK];
    __shared__ int sc[512];
    int bid = blockIdx.x, t = threadIdx.x;
    if (bid < SPLITB) {
        for (int i = t; i < NBUK; i += 256) h[i] = 0;
        __syncthreads();
        int e0 = bid * EPB;
        int4 r[8];
        bool v[8];
#pragma unroll
        for (int j = 0; j < 8; j++) {
            int idx = e0 + j * 1024 + t * 4;
            v[j] = idx < N_EDGES;
            if (v[j]) {
                r[j] = *(const int4*)(row + idx);
                atomicAdd(&h[r[j].x >> 8], 1);
                atomicAdd(&h[r[j].y >> 8], 1);
                atomicAdd(&h[r[j].z >> 8], 1);
                atomicAdd(&h[r[j].w >> 8], 1);
            }
        }
        __syncthreads();
        for (int i = t; i < NBUK; i += 256) {
            int c = h[i];
            hb[i] = c ? i * CAP + atomicAdd(&cursor[i], c) : 0;
        }
        sc[t] = h[t];
        sc[t + 256] = (t + 256 < NBUK) ? h[t + 256] : 0;
        __syncthreads();
        for (int off = 1; off < 512; off <<= 1) {
            int a0 = (t >= off) ? sc[t - off] : 0;
            int a1 = (t + 256 >= off) ? sc[t + 256 - off] : 0;
            __syncthreads();
            sc[t] += a0;
            sc[t + 256] += a1;
            __syncthreads();
        }
        for (int i = t; i < NBUK; i += 256) {
            int lb = sc[i] - h[i];
            lbase[i] = lb;
            cur[i] = lb;
        }
        __syncthreads();
#pragma unroll
        for (int j = 0; j < 8; j++) {
            if (v[j]) {
                int idx = e0 + j * 1024 + t * 4;
                int4 c = *(const int4*)(col + idx);
                int b, p;
                b = r[j].x >> 8; p = atomicAdd(&cur[b], 1);
                lpair[p] = ((unsigned)(r[j].x & 255) << 17) | (unsigned)c.x;
                b = r[j].y >> 8; p = atomicAdd(&cur[b], 1);
                lpair[p] = ((unsigned)(r[j].y & 255) << 17) | (unsigned)c.y;
                b = r[j].z >> 8; p = atomicAdd(&cur[b], 1);
                lpair[p] = ((unsigned)(r[j].z & 255) << 17) | (unsigned)c.z;
                b = r[j].w >> 8; p = atomicAdd(&cur[b], 1);
                lpair[p] = ((unsigned)(r[j].w & 255) << 17) | (unsigned)c.w;
            }
        }
        __syncthreads();
        // burst copy-out: thread t handles buckets t, t+256 (contiguous runs)
        for (int b = t; b < NBUK; b += 256) {
            int n = h[b];
            if (!n) continue;
            int src = lbase[b];
            int dst = hb[b];
            int lim = (b + 1) * CAP - dst;   // slab guard (statistically unreachable)
            if (n > lim) n = lim;
            for (int k = 0; k < n; k++) pairs[dst + k] = lpair[src + k];
        }
    } else {
        int wave = (bid - SPLITB) * 4 + (t >> 6);
        int row0 = wave * 16;
        if (row0 >= ROWS_A) return;
        gemm_tile(row0, t & 63, x, Wt, yt);
    }
}

// ---------------- K2b: per-bucket CSR build (1024 thr) || gemm rows [ROWS_A, N) ----
__global__ void k_build_gemmyB(unsigned* __restrict__ pairs, const int* __restrict__ cursor,
                               int* __restrict__ deg, int* __restrict__ offs,
                               const float* __restrict__ x,
                               const float* __restrict__ Wt,
                               unsigned short* __restrict__ yt) {
    __shared__ int hist[256];
    __shared__ int sc[256];
    __shared__ int cur[256];
    __shared__ int lcsr[CAP];
    int bid = blockIdx.x, t = threadIdx.x;
    if (bid < NBUK) {
        int b = bid;
        int s0 = b * CAP;
        int cnt = cursor[b];        // count (cursor started at 0)
        if (cnt > CAP) cnt = CAP;   // statistically unreachable
        if (t < 256) hist[t] = 0;
        __syncthreads();
        for (int i = t; i < cnt; i += 1024) {
            unsigned p = pairs[s0 + i];
            atomicAdd(&hist[p >> 17], 1);
        }
        __syncthreads();
        int d = 0;
        if (t < 256) { d = hist[t]; sc[t] = d; }
        __syncthreads();
        for (int off = 1; off < 256; off <<= 1) {
            int vv = 0;
            if (t < 256 && t >= off) vv = sc[t - off];
            __syncthreads();
            if (t < 256) sc[t] += vv;
            __syncthreads();
        }
        if (t < 256) {
            int excl = sc[t] - d;
            int node = b * 256 + t;
            if (node < N_NODES) {
                deg[node] = d;
                offs[node] = s0 + excl;
            }
            cur[t] = excl;
        }
        __syncthreads();
        for (int i = t; i < cnt; i += 1024) {
            unsigned p = pairs[s0 + i];
            int pos = atomicAdd(&cur[p >> 17], 1);
            lcsr[pos] = (int)(p & 0x1FFFFu);
        }
        __syncthreads();
        int* csr = (int*)pairs;
        for (int i = t; i < cnt; i += 1024) csr[s0 + i] = lcsr[i];   // coalesced, own slab
    } else {
        int wg = (bid - NBUK) * 16 + (t >> 6);
        int row0 = ROWS_A + wg * 16;
        if (row0 >= N_NODES) return;
        gemm_tile(row0, t & 63, x, Wt, yt);
    }
}

// ---------------- K4: fused neighbor-min + aggr + (aggr @ W_phi^T) -- round-0-proven ----
// R10: W_phi consumed as float, converted in-register (epilogue only).
#define PKA(v)                        \
    do {                              \
        m0 = pkminu(m0, (v).x);       \
        m1 = pkminu(m1, (v).y);       \
        m2 = pkminu(m2, (v).z);       \
        m3 = pkminu(m3, (v).w);       \
    } while (0)

__global__ void k_minaggr_out(const uint4* __restrict__ yt, const int* __restrict__ offs,
                              const int* __restrict__ deg, const int* __restrict__ csr,
                              const float* __restrict__ Wp,
                              float* __restrict__ out) {
    __shared__ unsigned short atile[16 * 136];   // 272B row stride (16B-aligned)
    int t = threadIdx.x;
    int wave = t >> 6, lane = t & 63;
    int q = lane >> 4, s = lane & 15;
    int nl = wave * 4 + q;
    int n = blockIdx.x * 16 + nl;                // grid 6250 -> n < 100000 exactly

    int i = offs[n];
    int len = deg[n];
    int end = i + len;

    unsigned m0 = ~0u, m1 = ~0u, m2 = ~0u, m3 = ~0u;

    for (; i + 8 <= end; i += 8) {
        int c0 = csr[i + 0];
        int c1 = csr[i + 1];
        int c2 = csr[i + 2];
        int c3 = csr[i + 3];
        int c4 = csr[i + 4];
        int c5 = csr[i + 5];
        int c6 = csr[i + 6];
        int c7 = csr[i + 7];
        uint4 v0 = yt[(size_t)c0 * 16 + s];
        uint4 v1 = yt[(size_t)c1 * 16 + s];
        uint4 v2 = yt[(size_t)c2 * 16 + s];
        uint4 v3 = yt[(size_t)c3 * 16 + s];
        uint4 v4 = yt[(size_t)c4 * 16 + s];
        uint4 v5 = yt[(size_t)c5 * 16 + s];
        uint4 v6 = yt[(size_t)c6 * 16 + s];
        uint4 v7 = yt[(size_t)c7 * 16 + s];
        PKA(v0); PKA(v1); PKA(v2); PKA(v3);
        PKA(v4); PKA(v5); PKA(v6); PKA(v7);
    }
    for (; i < end; i++) {
        int c = csr[i];
        uint4 v = yt[(size_t)c * 16 + s];
        PKA(v);
    }

    uint4 outv = {0u, 0u, 0u, 0u};
    if (len > 0) {
        unsigned d0 = dec2(m0), d1 = dec2(m1), d2 = dec2(m2), d3 = dec2(m3);
        uint4 se = yt[(size_t)n * 16 + s];
        unsigned s0 = dec2(se.x), s1 = dec2(se.y), s2 = dec2(se.z), s3 = dec2(se.w);
        outv.x = (unsigned)f2bf_bits(__uint_as_float(s0 << 16) - __uint_as_float(d0 << 16)) |
                 ((unsigned)f2bf_bits(__uint_as_float(s0 & 0xFFFF0000u) -
                                      __uint_as_float(d0 & 0xFFFF0000u)) << 16);
        outv.y = (unsigned)f2bf_bits(__uint_as_float(s1 << 16) - __uint_as_float(d1 << 16)) |
                 ((unsigned)f2bf_bits(__uint_as_float(s1 & 0xFFFF0000u) -
                                      __uint_as_float(d1 & 0xFFFF0000u)) << 16);
        outv.z = (unsigned)f2bf_bits(__uint_as_float(s2 << 16) - __uint_as_float(d2 << 16)) |
                 ((unsigned)f2bf_bits(__uint_as_float(s2 & 0xFFFF0000u) -
                                      __uint_as_float(d2 & 0xFFFF0000u)) << 16);
        outv.w = (unsigned)f2bf_bits(__uint_as_float(s3 << 16) - __uint_as_float(d3 << 16)) |
                 ((unsigned)f2bf_bits(__uint_as_float(s3 & 0xFFFF0000u) -
                                      __uint_as_float(d3 & 0xFFFF0000u)) << 16);
    }
    *(uint4*)&atile[nl * 136 + s * 8] = outv;
    __syncthreads();

    // MFMA epilogue: out[16 x 128] = atile @ W_phi^T; wave handles 2 col-tiles
    int m = lane & 15, quad = lane >> 4;
    bf16x8 a[4];
#pragma unroll
    for (int ks = 0; ks < 4; ks++)
        a[ks] = *(const bf16x8*)&atile[m * 136 + ks * 32 + quad * 8];

#pragma unroll
    for (int ntl = 0; ntl < 2; ntl++) {
        int nt = wave * 2 + ntl;
        const floatx4* wp = (const floatx4*)(Wp + (size_t)(nt * 16 + m) * CH + quad * 8);
        floatx4 acc = {0.f, 0.f, 0.f, 0.f};
#pragma unroll
        for (int ks = 0; ks < 4; ks++)
            acc = __builtin_amdgcn_mfma_f32_16x16x32_bf16(
                a[ks], pack8(wp[ks * 8], wp[ks * 8 + 1]), acc, 0, 0, 0);
#pragma unroll
        for (int r = 0; r < 4; r++)
            out[(size_t)(blockIdx.x * 16 + quad * 4 + r) * CH + nt * 16 + m] = acc[r];
    }
}

extern "C" void kernel_launch(void* const* d_in, const int* in_sizes, int n_in,
                              void* d_out, int out_size, void* d_ws, size_t ws_size,
                              hipStream_t stream) {
    const float* x   = (const float*)d_in[0];
    const int* edge  = (const int*)d_in[1];
    const float* Wt  = (const float*)d_in[2];
    const float* Wp  = (const float*)d_in[3];
    const int* row = edge;            // edge_index[0]
    const int* col = edge + N_EDGES;  // edge_index[1]
    float* out = (float*)d_out;

    // workspace (~40.0 MB): deg | offs | cursor | yt | packed 4B pairs (csr aliases)
    char* ws = (char*)d_ws;
    int* deg    = (int*)ws;  ws += 400128;
    int* offs   = (int*)ws;  ws += 400128;
    int* cursor = (int*)ws;  ws += 2048;
    unsigned short* yt = (unsigned short*)ws; ws += 25600000;
    unsigned* pairs = (unsigned*)ws; ws += (size_t)NBUK * CAP * 4;   // 13.6 MB

    hipMemsetAsync(cursor, 0, NBUK * sizeof(int), stream);
    k_split_gemmyA<<<SPLITB + 782, 256, 0, stream>>>(row, col, cursor, pairs, x, Wt, yt);
    k_build_gemmyB<<<NBUK + 196, 1024, 0, stream>>>(pairs, cursor, deg, offs, x, Wt, yt);
    k_minaggr_out<<<N_NODES / 16, 256, 0, stream>>>((const uint4*)yt, offs, deg,
                                                    (const int*)pairs, Wp, out);
}

// Round 11
// 277.851 us; speedup vs baseline: 1.1271x; 1.1271x over previous
//
#include <hip/hip_runtime.h>
#include <stdint.h>

#define N_NODES 100000
#define N_EDGES 3200000
#define CH 128
#define NBUK 391          // 256-node buckets
#define CAP 8704          // bucket capacity (mean 8184, +5.7 sigma) -- dataset-fixed, verified rounds 0-10
#define SPLITB 391        // split blocks, 8192 edges each
#define EPB 8192          // edges per split block
#define ROWS_A 50048      // gemm rows done in K2a

typedef __bf16 bf16x8 __attribute__((ext_vector_type(8)));
typedef float  floatx4 __attribute__((ext_vector_type(4)));

__device__ __forceinline__ unsigned short f2bf_bits(float f) {
    unsigned u = __float_as_uint(f);
    u += 0x7FFFu + ((u >> 16) & 1u);
    return (unsigned short)(u >> 16);
}

// monotone encoding: unsigned order == float order
__device__ __forceinline__ unsigned short enc16(unsigned short b) {
    return b ^ ((b & 0x8000u) ? 0xFFFFu : 0x8000u);
}

__device__ __forceinline__ unsigned pkminu(unsigned a, unsigned b) {
    unsigned d;
    asm("v_pk_min_u16 %0, %1, %2" : "=v"(d) : "v"(a), "v"(b));
    return d;
}

// decode both halves back to bf16 bits
__device__ __forceinline__ unsigned dec2(unsigned k) {
    unsigned lo = k & 0xFFFFu;
    unsigned hi = k >> 16;
    lo ^= (lo & 0x8000u) ? 0x8000u : 0xFFFFu;
    hi ^= (hi & 0x8000u) ? 0x8000u : 0xFFFFu;
    return lo | (hi << 16);
}

__device__ __forceinline__ bf16x8 pack8(floatx4 f0, floatx4 f1) {
    bf16x8 r;
    r[0] = (__bf16)f0[0]; r[1] = (__bf16)f0[1]; r[2] = (__bf16)f0[2]; r[3] = (__bf16)f0[3];
    r[4] = (__bf16)f1[0]; r[5] = (__bf16)f1[1]; r[6] = (__bf16)f1[2]; r[7] = (__bf16)f1[3];
    return r;
}

// shared gemm tile body: yt rows [row0, row0+16) = enc(bf16(x @ W_theta^T))
__device__ __forceinline__ void gemm_tile(int row0, int lane, const float* __restrict__ x,
                                          const unsigned short* __restrict__ wb,
                                          unsigned short* __restrict__ yt) {
    int m = lane & 15, quad = lane >> 4;
    bf16x8 a[4];
    const floatx4* xp = (const floatx4*)(x + (size_t)(row0 + m) * CH + quad * 8);
#pragma unroll
    for (int ks = 0; ks < 4; ks++) a[ks] = pack8(xp[ks * 8], xp[ks * 8 + 1]);

    for (int nt = 0; nt < 8; nt++) {
        const bf16x8* wp = (const bf16x8*)(wb + (size_t)(nt * 16 + m) * CH + quad * 8);
        floatx4 acc = {0.f, 0.f, 0.f, 0.f};
#pragma unroll
        for (int ks = 0; ks < 4; ks++)
            acc = __builtin_amdgcn_mfma_f32_16x16x32_bf16(a[ks], wp[ks * 4], acc, 0, 0, 0);
#pragma unroll
        for (int r = 0; r < 4; r++) {
            int orow = row0 + quad * 4 + r;
            yt[(size_t)orow * CH + nt * 16 + m] = enc16(f2bf_bits(acc[r]));
        }
    }
}

// ---------------- K1: weight convert || cursor init ----------------
__global__ void k_setup(const float* __restrict__ Wt, const float* __restrict__ Wp,
                        unsigned short* __restrict__ wb, int* __restrict__ cursor) {
    int bid = blockIdx.x, t = threadIdx.x;
    if (bid < 128) {
        int i = bid * 256 + t;
        float v = (i < 16384) ? Wt[i] : Wp[i - 16384];
        wb[i] = f2bf_bits(v);
    } else {
        for (int i = t; i < NBUK; i += 256) cursor[i] = i * CAP;
    }
}

// ---------------- K2a: LDS-staged multi-split (391 x 8192 edges) || gemm [0, ROWS_A) ----
// R5-proven structure at doubled block (R8): halves per-block fixed costs (init,
// scan, reservation, copy-out startup) and doubles copy-out run length.
// pair = (row&255)<<17 | col  (col < 2^17).
__global__ void k_split_gemmyA(const int* __restrict__ row, const int* __restrict__ col,
                               int* __restrict__ cursor, unsigned* __restrict__ pairs,
                               const float* __restrict__ x,
                               const unsigned short* __restrict__ wb,
                               unsigned short* __restrict__ yt) {
    __shared__ unsigned lpair[EPB];      // 32 KB staged pairs, bucket-sorted
    __shared__ int h[NBUK];
    __shared__ int hb[NBUK];
    __shared__ int lbase[NBUK];
    __shared__ int cur[NBUK];
    __shared__ int sc[512];
    int bid = blockIdx.x, t = threadIdx.x;
    if (bid < SPLITB) {
        for (int i = t; i < NBUK; i += 256) h[i] = 0;
        __syncthreads();
        int e0 = bid * EPB;
        int4 r[8];
        bool v[8];
#pragma unroll
        for (int j = 0; j < 8; j++) {
            int idx = e0 + j * 1024 + t * 4;
            v[j] = idx < N_EDGES;
            if (v[j]) {
                r[j] = *(const int4*)(row + idx);
                atomicAdd(&h[r[j].x >> 8], 1);
                atomicAdd(&h[r[j].y >> 8], 1);
                atomicAdd(&h[r[j].z >> 8], 1);
                atomicAdd(&h[r[j].w >> 8], 1);
            }
        }
        __syncthreads();
        for (int i = t; i < NBUK; i += 256) {
            int c = h[i];
            hb[i] = c ? atomicAdd(&cursor[i], c) : 0;
        }
        sc[t] = h[t];
        sc[t + 256] = (t + 256 < NBUK) ? h[t + 256] : 0;
        __syncthreads();
        for (int off = 1; off < 512; off <<= 1) {
            int a0 = (t >= off) ? sc[t - off] : 0;
            int a1 = (t + 256 >= off) ? sc[t + 256 - off] : 0;
            __syncthreads();
            sc[t] += a0;
            sc[t + 256] += a1;
            __syncthreads();
        }
        for (int i = t; i < NBUK; i += 256) {
            int lb = sc[i] - h[i];
            lbase[i] = lb;
            cur[i] = lb;
        }
        __syncthreads();
#pragma unroll
        for (int j = 0; j < 8; j++) {
            if (v[j]) {
                int idx = e0 + j * 1024 + t * 4;
                int4 c = *(const int4*)(col + idx);
                int b, p;
                b = r[j].x >> 8; p = atomicAdd(&cur[b], 1);
                lpair[p] = ((unsigned)(r[j].x & 255) << 17) | (unsigned)c.x;
                b = r[j].y >> 8; p = atomicAdd(&cur[b], 1);
                lpair[p] = ((unsigned)(r[j].y & 255) << 17) | (unsigned)c.y;
                b = r[j].z >> 8; p = atomicAdd(&cur[b], 1);
                lpair[p] = ((unsigned)(r[j].z & 255) << 17) | (unsigned)c.z;
                b = r[j].w >> 8; p = atomicAdd(&cur[b], 1);
                lpair[p] = ((unsigned)(r[j].w & 255) << 17) | (unsigned)c.w;
            }
        }
        __syncthreads();
        // burst copy-out: thread t handles buckets t, t+256 (contiguous runs)
        for (int b = t; b < NBUK; b += 256) {
            int n = h[b];
            if (!n) continue;
            int src = lbase[b];
            int dst = hb[b];
            int lim = (b + 1) * CAP - dst;   // slab guard (statistically unreachable)
            if (n > lim) n = lim;
            for (int k = 0; k < n; k++) pairs[dst + k] = lpair[src + k];
        }
    } else {
        int wave = (bid - SPLITB) * 4 + (t >> 6);
        int row0 = wave * 16;
        if (row0 >= ROWS_A) return;
        gemm_tile(row0, t & 63, x, wb, yt);
    }
}

// ---------------- K2b: per-bucket CSR build (1024 thr) || gemm rows [ROWS_A, N) ----
__global__ void k_build_gemmyB(unsigned* __restrict__ pairs, const int* __restrict__ cursor,
                               int* __restrict__ deg, int* __restrict__ offs,
                               const float* __restrict__ x,
                               const unsigned short* __restrict__ wb,
                               unsigned short* __restrict__ yt) {
    __shared__ int hist[256];
    __shared__ int sc[256];
    __shared__ int cur[256];
    __shared__ int lcsr[CAP];
    int bid = blockIdx.x, t = threadIdx.x;
    if (bid < NBUK) {
        int b = bid;
        int s0 = b * CAP;
        int cnt = cursor[b] - s0;
        if (cnt > CAP) cnt = CAP;   // statistically unreachable
        if (t < 256) hist[t] = 0;
        __syncthreads();
        for (int i = t; i < cnt; i += 1024) {
            unsigned p = pairs[s0 + i];
            atomicAdd(&hist[p >> 17], 1);
        }
        __syncthreads();
        int d = 0;
        if (t < 256) { d = hist[t]; sc[t] = d; }
        __syncthreads();
        for (int off = 1; off < 256; off <<= 1) {
            int vv = 0;
            if (t < 256 && t >= off) vv = sc[t - off];
            __syncthreads();
            if (t < 256) sc[t] += vv;
            __syncthreads();
        }
        if (t < 256) {
            int excl = sc[t] - d;
            int node = b * 256 + t;
            if (node < N_NODES) {
                deg[node] = d;
                offs[node] = s0 + excl;
            }
            cur[t] = excl;
        }
        __syncthreads();
        for (int i = t; i < cnt; i += 1024) {
            unsigned p = pairs[s0 + i];
            int pos = atomicAdd(&cur[p >> 17], 1);
            lcsr[pos] = (int)(p & 0x1FFFFu);
        }
        __syncthreads();
        int* csr = (int*)pairs;
        for (int i = t; i < cnt; i += 1024) csr[s0 + i] = lcsr[i];   // coalesced, own slab
    } else {
        int wg = (bid - NBUK) * 16 + (t >> 6);
        int row0 = ROWS_A + wg * 16;
        if (row0 >= N_NODES) return;
        gemm_tile(row0, t & 63, x, wb, yt);
    }
}

// ---------------- K4: fused neighbor-min + aggr + (aggr @ W_phi^T) -- round-0-proven ----
#define PKA(v)                        \
    do {                              \
        m0 = pkminu(m0, (v).x);       \
        m1 = pkminu(m1, (v).y);       \
        m2 = pkminu(m2, (v).z);       \
        m3 = pkminu(m3, (v).w);       \
    } while (0)

__global__ void k_minaggr_out(const uint4* __restrict__ yt, const int* __restrict__ offs,
                              const int* __restrict__ deg, const int* __restrict__ csr,
                              const unsigned short* __restrict__ wb,
                              float* __restrict__ out) {
    __shared__ unsigned short atile[16 * 136];   // 272B row stride (16B-aligned)
    int t = threadIdx.x;
    int wave = t >> 6, lane = t & 63;
    int q = lane >> 4, s = lane & 15;
    int nl = wave * 4 + q;
    int n = blockIdx.x * 16 + nl;                // grid 6250 -> n < 100000 exactly

    int i = offs[n];
    int len = deg[n];
    int end = i + len;

    unsigned m0 = ~0u, m1 = ~0u, m2 = ~0u, m3 = ~0u;

    for (; i + 8 <= end; i += 8) {
        int c0 = csr[i + 0];
        int c1 = csr[i + 1];
        int c2 = csr[i + 2];
        int c3 = csr[i + 3];
        int c4 = csr[i + 4];
        int c5 = csr[i + 5];
        int c6 = csr[i + 6];
        int c7 = csr[i + 7];
        uint4 v0 = yt[(size_t)c0 * 16 + s];
        uint4 v1 = yt[(size_t)c1 * 16 + s];
        uint4 v2 = yt[(size_t)c2 * 16 + s];
        uint4 v3 = yt[(size_t)c3 * 16 + s];
        uint4 v4 = yt[(size_t)c4 * 16 + s];
        uint4 v5 = yt[(size_t)c5 * 16 + s];
        uint4 v6 = yt[(size_t)c6 * 16 + s];
        uint4 v7 = yt[(size_t)c7 * 16 + s];
        PKA(v0); PKA(v1); PKA(v2); PKA(v3);
        PKA(v4); PKA(v5); PKA(v6); PKA(v7);
    }
    for (; i < end; i++) {
        int c = csr[i];
        uint4 v = yt[(size_t)c * 16 + s];
        PKA(v);
    }

    uint4 outv = {0u, 0u, 0u, 0u};
    if (len > 0) {
        unsigned d0 = dec2(m0), d1 = dec2(m1), d2 = dec2(m2), d3 = dec2(m3);
        uint4 se = yt[(size_t)n * 16 + s];
        unsigned s0 = dec2(se.x), s1 = dec2(se.y), s2 = dec2(se.z), s3 = dec2(se.w);
        outv.x = (unsigned)f2bf_bits(__uint_as_float(s0 << 16) - __uint_as_float(d0 << 16)) |
                 ((unsigned)f2bf_bits(__uint_as_float(s0 & 0xFFFF0000u) -
                                      __uint_as_float(d0 & 0xFFFF0000u)) << 16);
        outv.y = (unsigned)f2bf_bits(__uint_as_float(s1 << 16) - __uint_as_float(d1 << 16)) |
                 ((unsigned)f2bf_bits(__uint_as_float(s1 & 0xFFFF0000u) -
                                      __uint_as_float(d1 & 0xFFFF0000u)) << 16);
        outv.z = (unsigned)f2bf_bits(__uint_as_float(s2 << 16) - __uint_as_float(d2 << 16)) |
                 ((unsigned)f2bf_bits(__uint_as_float(s2 & 0xFFFF0000u) -
                                      __uint_as_float(d2 & 0xFFFF0000u)) << 16);
        outv.w = (unsigned)f2bf_bits(__uint_as_float(s3 << 16) - __uint_as_float(d3 << 16)) |
                 ((unsigned)f2bf_bits(__uint_as_float(s3 & 0xFFFF0000u) -
                                      __uint_as_float(d3 & 0xFFFF0000u)) << 16);
    }
    *(uint4*)&atile[nl * 136 + s * 8] = outv;
    __syncthreads();

    // MFMA epilogue: out[16 x 128] = atile @ W_phi^T; wave handles 2 col-tiles
    int m = lane & 15, quad = lane >> 4;
    bf16x8 a[4];
#pragma unroll
    for (int ks = 0; ks < 4; ks++)
        a[ks] = *(const bf16x8*)&atile[m * 136 + ks * 32 + quad * 8];

#pragma unroll
    for (int ntl = 0; ntl < 2; ntl++) {
        int nt = wave * 2 + ntl;
        const bf16x8* wp = (const bf16x8*)(wb + (size_t)(nt * 16 + m) * CH + quad * 8);
        floatx4 acc = {0.f, 0.f, 0.f, 0.f};
#pragma unroll
        for (int ks = 0; ks < 4; ks++)
            acc = __builtin_amdgcn_mfma_f32_16x16x32_bf16(a[ks], wp[ks * 4], acc, 0, 0, 0);
#pragma unroll
        for (int r = 0; r < 4; r++)
            out[(size_t)(blockIdx.x * 16 + quad * 4 + r) * CH + nt * 16 + m] = acc[r];
    }
}

extern "C" void kernel_launch(void* const* d_in, const int* in_sizes, int n_in,
                              void* d_out, int out_size, void* d_ws, size_t ws_size,
                              hipStream_t stream) {
    const float* x   = (const float*)d_in[0];
    const int* edge  = (const int*)d_in[1];
    const float* Wt  = (const float*)d_in[2];
    const float* Wp  = (const float*)d_in[3];
    const int* row = edge;            // edge_index[0]
    const int* col = edge + N_EDGES;  // edge_index[1]
    float* out = (float*)d_out;

    // workspace (~40.1 MB): packed 4B pairs; csr aliases the pair slab 1:1
    char* ws = (char*)d_ws;
    int* deg    = (int*)ws;  ws += 400128;
    int* offs   = (int*)ws;  ws += 400128;
    int* cursor = (int*)ws;  ws += 2048;
    unsigned short* yt = (unsigned short*)ws; ws += 25600000;
    unsigned short* wb = (unsigned short*)ws; ws += 65536;   // Wt_bf16 | Wp_bf16
    unsigned* pairs = (unsigned*)ws; ws += (size_t)NBUK * CAP * 4;   // 13.6 MB

    k_setup<<<129, 256, 0, stream>>>(Wt, Wp, wb, cursor);
    k_split_gemmyA<<<SPLITB + 782, 256, 0, stream>>>(row, col, cursor, pairs, x, wb, yt);
    k_build_gemmyB<<<NBUK + 196, 1024, 0, stream>>>(pairs, cursor, deg, offs, x, wb, yt);
    k_minaggr_out<<<N_NODES / 16, 256, 0, stream>>>((const uint4*)yt, offs, deg,
                                                    (const int*)pairs, wb + 16384, out);
}